// Round 6
// baseline (13198.167 us; speedup 1.0000x reference)
//
#include <hip/hip_runtime.h>
#include <cstdint>

#define SEQ   2048
#define BATCH 128
#define IN    64
#define HID   256
#define OUTD  64

#define T     512
#define NREG  20   // 8-dim chunks per row in registers: dims 0..159  (160 dw/thread, pinned)
#define NLDSW 8    // 8-dim chunks per row in LDS:       dims 160..223 (131 KB LDS)
#define NSTR  4    // 8-dim chunks per row hoisted/streamed: dims 224..255 (32 dw/thread)
#define NIH   8    // W_ih 8-dim chunks per row (64 input dims, 32 dw/thread)

// ---- ws layout in dwords (read-only in lstm_main: loads are loop-invariant) ----
#define OFF_REG  0
#define SZ_REG   (2*NREG*512*4)          // 81920
#define OFF_LDSW (OFF_REG+SZ_REG)        // 81920
#define SZ_LDSW  (2*NLDSW*512*4)         // 32768
#define OFF_STR  (OFF_LDSW+SZ_LDSW)      // 114688
#define SZ_STR   (2*NSTR*512*4)          // 16384
#define OFF_WIH  (OFF_STR+SZ_STR)        // 131072
#define SZ_WIH   (2*NIH*512*4)           // 32768
#define OFF_WOUT (OFF_WIH+SZ_WIH)        // 163840
#define SZ_WOUT  8192                    // 64*256 f16
#define TOTAL_DW (OFF_WOUT+SZ_WOUT)      // 172032 dw = 688 KB

typedef _Float16 f16x2 __attribute__((ext_vector_type(2)));

__device__ __forceinline__ float fexp2(float v) { return __builtin_amdgcn_exp2f(v); }
__device__ __forceinline__ float frcp(float v)  { return __builtin_amdgcn_rcpf(v); }
__device__ __forceinline__ float fsig(float v)  { return frcp(1.0f + fexp2(v * -1.44269504088896f)); }
__device__ __forceinline__ float ftanh_(float v){ return 1.0f - 2.0f * frcp(1.0f + fexp2(v * 2.88539008177793f)); }

__device__ __forceinline__ unsigned int pack2d(float a, float b) {
  unsigned short lo = __builtin_bit_cast(unsigned short, (_Float16)a);
  unsigned short hi = __builtin_bit_cast(unsigned short, (_Float16)b);
  return (unsigned int)lo | ((unsigned int)hi << 16);
}

__device__ __forceinline__ float dot2f(unsigned int w, unsigned int h, float acc) {
#if __has_builtin(__builtin_amdgcn_fdot2)
  return __builtin_amdgcn_fdot2(__builtin_bit_cast(f16x2, w), __builtin_bit_cast(f16x2, h), acc, false);
#else
  f16x2 a = __builtin_bit_cast(f16x2, w), b = __builtin_bit_cast(f16x2, h);
  return acc + (float)a.x * (float)b.x + (float)a.y * (float)b.y;
#endif
}

__device__ __forceinline__ void mac8(uint4 w, uint4 h, float& acc) {
  acc = dot2f(w.x, h.x, acc);
  acc = dot2f(w.y, h.y, acc);
  acc = dot2f(w.z, h.z, acc);
  acc = dot2f(w.w, h.w, acc);
}

// Pin a loaded value into registers (asm-defined -> cannot be rematerialized as a load).
#define PIN4(v) asm volatile("" : "+v"((v).x), "+v"((v).y), "+v"((v).z), "+v"((v).w))

// ---------------- prep: fp32 weights -> packed f16 layouts in ws ----------------
__global__ void prep_weights(const float* __restrict__ Whh, const float* __restrict__ Wih,
                             const float* __restrict__ Wout, unsigned int* __restrict__ ws) {
  int tid = blockIdx.x * 256 + threadIdx.x;
  if (tid >= TOTAL_DW) return;
  unsigned int val;
  if (tid < OFF_LDSW) {                            // W_hh register part: dims 0..159
    int q = tid & 3, t = (tid >> 2) & 511, rest = tid >> 11;  // rest 0..39
    int j = rest % NREG, r = rest / NREG;
    const float* p = Whh + (size_t)(r*512 + t)*HID + 8*j + 2*q;
    val = pack2d(p[0], p[1]);
  } else if (tid < OFF_STR) {                      // W_hh LDS part: dims 160..223
    int rr = tid - OFF_LDSW;
    int q = rr & 3, t = (rr >> 2) & 511, rest = rr >> 11;     // rest 0..15
    int j = rest & 7, r = rest >> 3;
    const float* p = Whh + (size_t)(r*512 + t)*HID + 160 + 8*j + 2*q;
    val = pack2d(p[0], p[1]);
  } else if (tid < OFF_WIH) {                      // W_hh streamed part: dims 224..255
    int rr = tid - OFF_STR;
    int q = rr & 3, t = (rr >> 2) & 511, rest = rr >> 11;     // rest 0..7
    int j = rest & 3, r = rest >> 2;
    const float* p = Whh + (size_t)(r*512 + t)*HID + 224 + 8*j + 2*q;
    val = pack2d(p[0], p[1]);
  } else if (tid < OFF_WOUT) {                     // W_ih: dims 0..63
    int rr = tid - OFF_WIH;
    int q = rr & 3, t = (rr >> 2) & 511, rest = rr >> 11;     // rest 0..15
    int j = rest & 7, r = rest >> 3;
    const float* p = Wih + (size_t)(r*512 + t)*IN + 8*j + 2*q;
    val = pack2d(p[0], p[1]);
  } else {                                         // W_out linear f16
    int rr = tid - OFF_WOUT;
    const float* p = Wout + 2*rr;
    val = pack2d(p[0], p[1]);
  }
  ws[tid] = val;
}

// ---------------- main: ONE block per batch element (grid = 128) ----------------
// Thread t owns gate rows t and t+512. W_hh split per row: dims 0..159 pinned in
// VGPR/AGPR (PIN4, proven r3), dims 160..223 in LDS (131 KB, lane-consecutive ->
// conflict-free b128 reads), dims 224..255 + W_ih + W_out loaded loop-invariantly
// (ws is never written here -> hoisting is legal; graceful sink if regs run out).
// No inter-block communication of any kind: no atomics, no spins -> cannot hang.
// 136 KB LDS -> 1 block/CU. h/x broadcast from LDS; readout from padded hs2 copy.
__global__ __launch_bounds__(512, 2) void lstm_main(
    const float* __restrict__ x, const float* __restrict__ h0, const float* __restrict__ c0,
    const float* __restrict__ bias, const float* __restrict__ b_out,
    const unsigned int* __restrict__ ws, float* __restrict__ out)
{
  const int b = blockIdx.x, t = threadIdx.x;

  __shared__ __align__(16) unsigned int wlds[2*NLDSW*512*4];  // 131072 B
  __shared__ __align__(16) float lin_sh[1024];                // 4 KiB
  __shared__ __align__(16) unsigned short hs[HID];            // h_s linear (broadcast reads)
  __shared__ __align__(16) unsigned short hs2[8*40];          // h_s padded for readout (80B stride)
  __shared__ __align__(16) unsigned short xs[IN];             // x_s

  const unsigned int* WregS = ws + OFF_REG;
  const unsigned int* WldsS = ws + OFF_LDSW;
  const unsigned int* WstrS = ws + OFF_STR;
  const unsigned int* WihS  = ws + OFF_WIH;
  const unsigned short* WoutS = (const unsigned short*)(ws + OFF_WOUT);

  // ---- pinned register weights: W_hh dims 0..159 for rows t and t+512 ----
  uint4 whh0[NREG], whh1[NREG];
  #pragma unroll
  for (int j = 0; j < NREG; ++j) {
    whh0[j] = *(const uint4*)(WregS + ((size_t)(0*NREG + j)*512 + t)*4);
    PIN4(whh0[j]);
    whh1[j] = *(const uint4*)(WregS + ((size_t)(1*NREG + j)*512 + t)*4);
    PIN4(whh1[j]);
  }
  // ---- readout weights (pinned): o = t>>3 over dims seg*32..seg*32+31 ----
  const int o = t >> 3, seg = t & 7;
  uint4 wo[4];
  #pragma unroll
  for (int q = 0; q < 4; ++q) {
    wo[q] = *(const uint4*)(WoutS + (size_t)o*256 + seg*32 + 8*q);
    PIN4(wo[q]);
  }
  // ---- loop-invariant unpinned loads (compiler hoists what fits) ----
  uint4 wst0[NSTR], wst1[NSTR];
  #pragma unroll
  for (int j = 0; j < NSTR; ++j) {
    wst0[j] = *(const uint4*)(WstrS + ((size_t)(0*NSTR + j)*512 + t)*4);
    wst1[j] = *(const uint4*)(WstrS + ((size_t)(1*NSTR + j)*512 + t)*4);
  }
  uint4 wih0[NIH], wih1[NIH];
  #pragma unroll
  for (int j = 0; j < NIH; ++j) {
    wih0[j] = *(const uint4*)(WihS + ((size_t)(0*NIH + j)*512 + t)*4);
    wih1[j] = *(const uint4*)(WihS + ((size_t)(1*NIH + j)*512 + t)*4);
  }
  // ---- LDS weight slice: dims 160..223, both rows ----
  #pragma unroll
  for (int v = 0; v < 2*NLDSW; ++v) {
    int idx = (v*512 + t)*4;
    *(uint4*)(wlds + idx) = *(const uint4*)(WldsS + idx);
  }

  // ---- state init ----
  float c = 0.0f;
  if (t < HID) {
    c = c0[(size_t)b*HID + t];
    unsigned short hv0 = (unsigned short)(pack2d(h0[(size_t)b*HID + t], 0.0f) & 0xffffu);
    hs[t] = hv0;
    hs2[(t >> 5)*40 + (t & 31)] = hv0;
  } else if (t < HID + 32) {
    int i = t - HID;
    float2 xx = *(const float2*)(x + (size_t)b*IN + 2*i);   // x at s=0
    ((unsigned int*)xs)[i] = pack2d(xx.x, xx.y);
  }
  const float bz0 = bias[t], bz1 = bias[t + 512];
  const float bo  = b_out[o];
  __syncthreads();

  for (int s = 0; s < SEQ; ++s) {
    // x_{s+1} prefetch: issue early, consumed after barrier (a)
    float2 xn = make_float2(0.0f, 0.0f);
    if (t >= HID && t < HID + 32) {
      int sn = (s + 1 < SEQ) ? s + 1 : s;
      xn = *(const float2*)(x + ((size_t)sn*BATCH + b)*IN + 2*(t - HID));
    }

    float la = bz0, lb = bz1;   // two chains, one per owned row, interleaved
    // register part: dims 0..159
    #pragma unroll
    for (int j = 0; j < NREG; ++j) {
      uint4 hv = *(const uint4*)(hs + 8*j);
      mac8(whh0[j], hv, la);
      mac8(whh1[j], hv, lb);
    }
    // LDS part: dims 160..223
    #pragma unroll
    for (int j = 0; j < NLDSW; ++j) {
      uint4 hv = *(const uint4*)(hs + 160 + 8*j);
      uint4 w0 = *(const uint4*)(wlds + ((0*NLDSW + j)*512 + t)*4);
      uint4 w1 = *(const uint4*)(wlds + ((1*NLDSW + j)*512 + t)*4);
      mac8(w0, hv, la);
      mac8(w1, hv, lb);
    }
    // hoisted/streamed tail: dims 224..255
    #pragma unroll
    for (int j = 0; j < NSTR; ++j) {
      uint4 hv = *(const uint4*)(hs + 224 + 8*j);
      mac8(wst0[j], hv, la);
      mac8(wst1[j], hv, lb);
    }
    // x projection
    #pragma unroll
    for (int j = 0; j < NIH; ++j) {
      uint4 xv = *(const uint4*)(xs + 8*j);
      mac8(wih0[j], xv, la);
      mac8(wih1[j], xv, lb);
    }
    lin_sh[t]       = la;
    lin_sh[t + 512] = lb;

    __syncthreads();  // (a) lin complete

    if (t < HID) {
      float li  = lin_sh[t];
      float lf  = lin_sh[t + 256];
      float lg  = lin_sh[t + 512];
      float lo_ = lin_sh[t + 768];
      float ig = fsig(li), fg = fsig(lf), gg = ftanh_(lg), og = fsig(lo_);
      c = fg*c + ig*gg;
      float hn = og*ftanh_(c);
      unsigned short hp = (unsigned short)(pack2d(hn, 0.0f) & 0xffffu);
      hs[t] = hp;
      hs2[(t >> 5)*40 + (t & 31)] = hp;
    } else if (t < HID + 32) {
      ((unsigned int*)xs)[t - HID] = pack2d(xn.x, xn.y);
    }
    __syncthreads();  // (b) h_{s+1} / x_{s+1} published

    // fused readout: out[s,b,o] = W_out[o,:]·h_{s+1} + b_out[o]  (matches reference scan output)
    float acc = 0.0f;
    #pragma unroll
    for (int q = 0; q < 4; ++q) {
      uint4 hv = *(const uint4*)(hs2 + seg*40 + 8*q);
      mac8(wo[q], hv, acc);
    }
    acc += __shfl_xor(acc, 1);
    acc += __shfl_xor(acc, 2);
    acc += __shfl_xor(acc, 4);
    if (seg == 0) out[((size_t)s*BATCH + b)*OUTD + o] = acc + bo;
  }
}

extern "C" void kernel_launch(void* const* d_in, const int* in_sizes, int n_in,
                              void* d_out, int out_size, void* d_ws, size_t ws_size,
                              hipStream_t stream) {
  const float* x     = (const float*)d_in[0];
  const float* h0    = (const float*)d_in[1];
  const float* c0    = (const float*)d_in[2];
  const float* W_ih  = (const float*)d_in[3];
  const float* W_hh  = (const float*)d_in[4];
  const float* bias  = (const float*)d_in[5];
  const float* W_out = (const float*)d_in[6];
  const float* b_out = (const float*)d_in[7];
  float* out = (float*)d_out;
  unsigned int* ws = (unsigned int*)d_ws;

  hipLaunchKernelGGL(prep_weights, dim3((TOTAL_DW + 255)/256), dim3(256), 0, stream,
                     W_hh, W_ih, W_out, ws);
  hipLaunchKernelGGL(lstm_main, dim3(BATCH), dim3(T), 0, stream,
                     x, h0, c0, bias, b_out, ws, out);
}